// Round 3
// baseline (500.442 us; speedup 1.0000x reference)
//
#include <hip/hip_runtime.h>
#include <stdint.h>

// ---------------------------------------------------------------------------
// KnowledgeCircuit: B=4 S=2048 D=1024 N=64 R=128, M = B*S = 8192 tokens.
// Stage 1: h[m,r]   = sum_n w1[m,n] * (sum_d x[m,d] F[n,d,r])     K=65536
// Stage 2: out[m,d] = sum_n w2[m,n] * (sum_r h[m,r] Rk[n,r,d])    K=8192
// Round 3: occupancy tier 2->4 waves/SIMD. Block tile 64x128, wave tile 32x64
// (acc_in+acc_out = 64 regs), BK=64, LDS 24 KB/block, 1024-block grids.
// ---------------------------------------------------------------------------

typedef unsigned short ushort_t;
typedef __attribute__((ext_vector_type(8))) short frag_t;   // 8 bf16
typedef __attribute__((ext_vector_type(4))) float f32x4;

#define BK 64

__device__ __forceinline__ unsigned short f2bf(float f) {
    unsigned int u = __builtin_bit_cast(unsigned int, f);
    u = (u + 0x7FFFu + ((u >> 16) & 1u)) >> 16;   // RTNE
    return (unsigned short)u;
}

__device__ __forceinline__ void glds16(const ushort_t* g, ushort_t* l) {
    __builtin_amdgcn_global_load_lds(
        (const __attribute__((address_space(1))) unsigned int*)g,
        (__attribute__((address_space(3))) unsigned int*)l,
        16, 0, 0);
}

// ---------------- prepass: fp32 -> bf16 elementwise -------------------------
__global__ __launch_bounds__(256) void convert_bf(const float* __restrict__ in,
                                                  ushort_t* __restrict__ out, int n8) {
    int idx = blockIdx.x * 256 + threadIdx.x;
    if (idx >= n8) return;
    const float4 v0 = ((const float4*)in)[idx * 2];
    const float4 v1 = ((const float4*)in)[idx * 2 + 1];
    unsigned short b[8] = { f2bf(v0.x), f2bf(v0.y), f2bf(v0.z), f2bf(v0.w),
                            f2bf(v1.x), f2bf(v1.y), f2bf(v1.z), f2bf(v1.w) };
    ((uint4*)out)[idx] = *(const uint4*)b;
}

// ---------------- prepass: fp32 RxC -> bf16 CxR transpose -------------------
__global__ __launch_bounds__(256) void transpose_bf(const float* __restrict__ in,
                                                    ushort_t* __restrict__ out,
                                                    int R, int C) {
    __shared__ float tile[64][65];
    const int t  = threadIdx.x;
    const int r0 = blockIdx.x * 64;
    const int c0 = blockIdx.y * 64;
    const int ci = t & 63;
    const int rb = t >> 6;
    #pragma unroll
    for (int p = 0; p < 16; ++p)
        tile[rb + 4 * p][ci] = in[(size_t)(r0 + rb + 4 * p) * C + c0 + ci];
    __syncthreads();
    const int cw = t >> 2;          // 0..63 output row (input col)
    const int rg = (t & 3) * 16;    // 16 consecutive r per thread
    unsigned short buf[16];
    #pragma unroll
    for (int k = 0; k < 16; ++k)
        buf[k] = f2bf(tile[rg + k][cw]);
    uint4* dst = (uint4*)&out[(size_t)(c0 + cw) * R + r0 + rg];
    dst[0] = *(const uint4*)&buf[0];
    dst[1] = *(const uint4*)&buf[8];
}

// ---------------- main GEMM -------------------------------------------------
// A[m,k] = W[m, k>>SHIFT] * Ab[m, k & mask]   (scale deferred to fold)
// B[k,n] = Bt[n, k]   (pre-transposed, k-contiguous)
// Block tile 64(M) x 128(N), wave tile 32x64 in a 2x2 wave grid, BK=64.
template<int SHIFT, int SEG_STEPS, bool ATOMIC>
__global__ __launch_bounds__(256, 4)
void kc_gemm(const ushort_t* __restrict__ Ab, const float* __restrict__ W,
             const ushort_t* __restrict__ Bt, float* __restrict__ C,
             int ldA, int ldB, int ldC, int ksteps)
{
    __shared__ ushort_t As[64 * BK];    //  8 KB: row = 8 chunks of 16B, XOR-swizzled
    __shared__ ushort_t Bs[128 * BK];   // 16 KB

    const int t    = threadIdx.x;
    const int lane = t & 63;
    const int wv   = t >> 6;
    const int m0   = blockIdx.x * 64;
    const int n0   = blockIdx.y * 128;
    const int kbase = blockIdx.z * ksteps * BK;

    const int wm = (wv & 1) * 32;
    const int wn = (wv >> 1) * 64;
    const int fr = lane & 15;
    const int q  = lane >> 4;
    const int e  = fr & 7;

    // staging maps (XOR swizzle applied to the GLOBAL source column so the
    // wave-uniform-base glds deposit lands chunks at slot c^(row&7))
    int arow[2], acol[2];
    #pragma unroll
    for (int c = 0; c < 2; ++c) {
        const int s = (wv * 2 + c) * 64 + lane;
        arow[c] = s >> 3;
        acol[c] = ((s & 7) ^ (arow[c] & 7)) * 8;
    }
    int brow[4], bcol[4];
    #pragma unroll
    for (int c = 0; c < 4; ++c) {
        const int s = (wv * 4 + c) * 64 + lane;
        brow[c] = s >> 3;
        bcol[c] = ((s & 7) ^ (brow[c] & 7)) * 8;
    }

    f32x4 acc_out[2][4];
    #pragma unroll
    for (int i = 0; i < 2; ++i)
        #pragma unroll
        for (int j = 0; j < 4; ++j)
            acc_out[i][j] = (f32x4){0.f, 0.f, 0.f, 0.f};

    const int nsegs = ksteps / SEG_STEPS;
    for (int seg = 0; seg < nsegs; ++seg) {
        const int segk = kbase + seg * SEG_STEPS * BK;
        const int nidx = segk >> SHIFT;

        f32x4 acc_in[2][4];
        #pragma unroll
        for (int i = 0; i < 2; ++i)
            #pragma unroll
            for (int j = 0; j < 4; ++j)
                acc_in[i][j] = (f32x4){0.f, 0.f, 0.f, 0.f};

        for (int ss = 0; ss < SEG_STEPS; ++ss) {
            const int k0 = segk + ss * BK;
            const int d0 = k0 & ((1 << SHIFT) - 1);

            __syncthreads();   // prior frag reads done before overwrite
            #pragma unroll
            for (int c = 0; c < 2; ++c)
                glds16(Ab + (size_t)(m0 + arow[c]) * ldA + d0 + acol[c],
                       &As[(wv * 2 + c) * 512]);
            #pragma unroll
            for (int c = 0; c < 4; ++c)
                glds16(Bt + (size_t)(n0 + brow[c]) * ldB + k0 + bcol[c],
                       &Bs[(wv * 4 + c) * 512]);
            __syncthreads();   // drains vmcnt (global_load_lds)

            #pragma unroll
            for (int kk = 0; kk < 2; ++kk) {
                const int csw = (kk * 4 + q) ^ e;
                frag_t a[2], b[4];
                #pragma unroll
                for (int i = 0; i < 2; ++i)
                    a[i] = *(const frag_t*)&As[((wm + 16 * i + fr) * 8 + csw) * 8];
                #pragma unroll
                for (int j = 0; j < 4; ++j)
                    b[j] = *(const frag_t*)&Bs[((wn + 16 * j + fr) * 8 + csw) * 8];
                #pragma unroll
                for (int i = 0; i < 2; ++i)
                    #pragma unroll
                    for (int j = 0; j < 4; ++j)
                        acc_in[i][j] = __builtin_amdgcn_mfma_f32_16x16x32_bf16(
                                           a[i], b[j], acc_in[i][j], 0, 0, 0);
            }
        }

        // fold: acc_out += W[m, nidx] * acc_in   (W broadcast across fr lanes)
        #pragma unroll
        for (int i = 0; i < 2; ++i) {
            #pragma unroll
            for (int r = 0; r < 4; ++r) {
                const int gm = m0 + wm + 16 * i + q * 4 + r;
                const float w = W[(size_t)gm * 64 + nidx];
                #pragma unroll
                for (int j = 0; j < 4; ++j)
                    acc_out[i][j][r] += w * acc_in[i][j][r];
            }
        }
    }

    // epilogue: C/D layout col=lane&15, row=q*4+reg
    #pragma unroll
    for (int i = 0; i < 2; ++i) {
        #pragma unroll
        for (int j = 0; j < 4; ++j) {
            #pragma unroll
            for (int r = 0; r < 4; ++r) {
                const int gm = m0 + wm + 16 * i + q * 4 + r;
                const int gn = n0 + wn + 16 * j + fr;
                if constexpr (ATOMIC)
                    atomicAdd(&C[(size_t)gm * ldC + gn], acc_out[i][j][r]);
                else
                    C[(size_t)gm * ldC + gn] = acc_out[i][j][r];
            }
        }
    }
}

extern "C" void kernel_launch(void* const* d_in, const int* in_sizes, int n_in,
                              void* d_out, int out_size, void* d_ws, size_t ws_size,
                              hipStream_t stream) {
    const float* x  = (const float*)d_in[0];   // [8192, 1024]
    const float* w1 = (const float*)d_in[1];   // [8192, 64]
    const float* w2 = (const float*)d_in[2];   // [8192, 64]
    const float* F  = (const float*)d_in[3];   // (65536, 128) k-major
    const float* Rk = (const float*)d_in[4];   // (8192, 1024) k-major
    float* out = (float*)d_out;                // [8192, 1024]

    char* ws = (char*)d_ws;
    float*    h    = (float*)ws;                           //  4 MB fp32
    ushort_t* buf1 = (ushort_t*)(ws + ((size_t)4  << 20)); // 16 MB: x_bf, then Rk_t
    ushort_t* F_t  = (ushort_t*)(ws + ((size_t)20 << 20)); // 16 MB
    ushort_t* h_bf = (ushort_t*)(ws + ((size_t)36 << 20)); //  2 MB
    // total footprint: 38 MB

    hipMemsetAsync(h, 0, (size_t)8192 * 128 * sizeof(float), stream);

    // prepasses for stage 1
    convert_bf<<<4096, 256, 0, stream>>>(x, buf1, 1048576);                 // x -> bf16
    transpose_bf<<<dim3(1024, 2), 256, 0, stream>>>(F, F_t, 65536, 128);    // F_t[128,65536]

    // Stage 1: M=8192 K=65536 N=128, split-K z=8 (8 n-segments per chunk)
    // grid 128 x 1 x 8 = 1024 blocks, ksteps = 8192/64 = 128, SEG = 1024/64 = 16
    kc_gemm<10, 16, true><<<dim3(128, 1, 8), 256, 0, stream>>>(
        buf1, w1, F_t, h, 1024, 65536, 128, 128);

    // prepasses for stage 2 (Rk_t overlays buf1 — x_bf dead now)
    convert_bf<<<512, 256, 0, stream>>>(h, h_bf, 131072);                   // h -> bf16
    transpose_bf<<<dim3(128, 16), 256, 0, stream>>>(Rk, buf1, 8192, 1024);  // Rk_t[1024,8192]

    // Stage 2: M=8192 K=8192 N=1024
    // grid 128 x 8 x 1 = 1024 blocks, ksteps = 128, SEG = 128/64 = 2
    kc_gemm<7, 2, false><<<dim3(128, 8, 1), 256, 0, stream>>>(
        h_bf, w2, buf1, out, 128, 8192, 1024, 128);
}